// Round 2
// baseline (274.354 us; speedup 1.0000x reference)
//
#include <hip/hip_runtime.h>
#include <hip/hip_cooperative_groups.h>
#include <math.h>

namespace cg = cooperative_groups;

// Problem sizes (fixed by the reference)
#define B   4
#define TQ  256
#define TV  1024
#define D   512
#define A   128

#define LOG2E     1.4426950408889634f
#define TWO_LOG2E 2.8853900817779268f
#define NEG_BIG_F (-1e9f)

#define QBLK (B * TQ / 8)   // 128 q-projection blocks (fallback path)
#define KBLK (B * TV / 8)   // 512 k-projection blocks (fallback path)

// ===========================================================================
// ROUND-13: single fused cooperative kernel, 512 blocks x 512 threads.
//   Phase 1a: k projection (8 rows/block, d-split 8 waves) -> EkT (transposed)
//   Phase 1b: q projection (2 rows/block, same structure)  -> Eq
//   grid.sync()
//   Phase 2 : score + softmax (2 q rows/block, XCD-swizzled) -> attn
//   grid.sync()
//   Phase 3 : pv (b,dt,qt XCD-swizzled)                      -> out
// Rationale: removes 2 kernel-boundary drains/dispatches; proj work is
// perfectly rebalanced (10 rows per block, no tail). LDS: 32KB tile buffer
// shared between phase-1 partials (ps[8][8][128]) and phase-3 attn tile,
// + 4.6KB transpose staging => 37.5KB, 2 blocks/CU co-resident (=512 blocks).
// ===========================================================================
__global__ __launch_bounds__(512, 4) void fused_kernel(
    const float* __restrict__ ctx, const float* __restrict__ inp,
    const float* __restrict__ Wq, const float* __restrict__ bq,
    const float* __restrict__ Wk, const float* __restrict__ bk,
    const float* __restrict__ attn_v, const int* __restrict__ mask,
    float* __restrict__ Eq, float* __restrict__ EkT,
    float* __restrict__ attn, float* __restrict__ out) {
  __shared__ float lds[8 * 1024];   // 32 KB: ps[8][8][A] in ph1, attn tile ph3
  __shared__ float es[A][9];        // 4.6 KB transpose staging (ph1a)
  __shared__ float redA[8], redB[8];
  __shared__ float bc[4];

  int tid = threadIdx.x;
  int g   = tid >> 6;             // wave id 0..7 (wave-uniform)
  int ap  = (tid & 63) * 2;       // a-pair base
  float (*ps)[8][A] = (float (*)[8][A])lds;   // [row j][wave g][a]

  int dbase = __builtin_amdgcn_readfirstlane(g * 64);

  // ------------------- Phase 1a: k projection, 8 rows -------------------
  {
    int r0 = blockIdx.x * 8;                    // k row block (0..4095)
    const float* Xr = inp + (size_t)r0 * D + dbase;
    const float* Wd = Wk + (size_t)dbase * A + ap;

    float2 acc[8];
#pragma unroll
    for (int j = 0; j < 8; ++j) acc[j] = make_float2(0.f, 0.f);

#pragma unroll 2
    for (int dd = 0; dd < 64; dd += 4) {
      float2 w0 = *(const float2*)(Wd + (size_t)(dd + 0) * A);
      float2 w1 = *(const float2*)(Wd + (size_t)(dd + 1) * A);
      float2 w2 = *(const float2*)(Wd + (size_t)(dd + 2) * A);
      float2 w3 = *(const float2*)(Wd + (size_t)(dd + 3) * A);
      float4 x[8];
#pragma unroll
      for (int j = 0; j < 8; ++j)
        x[j] = *(const float4*)(Xr + (size_t)j * D + dd);   // scalar s_load
#pragma unroll
      for (int j = 0; j < 8; ++j) {
        acc[j].x = fmaf(x[j].x, w0.x, acc[j].x);
        acc[j].y = fmaf(x[j].x, w0.y, acc[j].y);
        acc[j].x = fmaf(x[j].y, w1.x, acc[j].x);
        acc[j].y = fmaf(x[j].y, w1.y, acc[j].y);
        acc[j].x = fmaf(x[j].z, w2.x, acc[j].x);
        acc[j].y = fmaf(x[j].z, w2.y, acc[j].y);
        acc[j].x = fmaf(x[j].w, w3.x, acc[j].x);
        acc[j].y = fmaf(x[j].w, w3.y, acc[j].y);
      }
    }

#pragma unroll
    for (int j = 0; j < 8; ++j)
      *(float2*)&ps[j][g][ap] = acc[j];
    __syncthreads();

    // reduce 8 wave-partials: row j = tid>>6, a-pair per lane
    int j  = tid >> 6;
    int a2 = (tid & 63) * 2;
    float2 s0 = *(const float2*)&ps[j][0][a2];
    float2 s1 = *(const float2*)&ps[j][1][a2];
    float2 s2 = *(const float2*)&ps[j][2][a2];
    float2 s3 = *(const float2*)&ps[j][3][a2];
    float2 s4 = *(const float2*)&ps[j][4][a2];
    float2 s5 = *(const float2*)&ps[j][5][a2];
    float2 s6 = *(const float2*)&ps[j][6][a2];
    float2 s7 = *(const float2*)&ps[j][7][a2];
    float2 bz = *(const float2*)(bk + a2);
    float2 ev;
    ev.x = __builtin_amdgcn_exp2f(
        ((((s0.x + s1.x) + (s2.x + s3.x)) + ((s4.x + s5.x) + (s6.x + s7.x))) + bz.x) * TWO_LOG2E);
    ev.y = __builtin_amdgcn_exp2f(
        ((((s0.y + s1.y) + (s2.y + s3.y)) + ((s4.y + s5.y) + (s6.y + s7.y))) + bz.y) * TWO_LOG2E);

    es[a2 + 0][j] = ev.x;
    es[a2 + 1][j] = ev.y;
    __syncthreads();          // all ps reads + es writes complete

    int b  = r0 >> 10;        // TV == 1024
    int v0 = r0 & (TV - 1);
    for (int i = tid; i < A * 8; i += 512) {
      int aa = i >> 3, jj = i & 7;
      EkT[((size_t)b * A + aa) * TV + v0 + jj] = es[aa][jj];
    }
    // no sync needed: q-phase writes ps (not es), and all ps reads are done
  }

  // ------------------- Phase 1b: q projection, 2 rows -------------------
  {
    int r0 = blockIdx.x * 2;                    // q row pair (0..1023)
    const float* Xr = ctx + (size_t)r0 * D + dbase;
    const float* Wd = Wq + (size_t)dbase * A + ap;

    float2 a0 = make_float2(0.f, 0.f);
    float2 a1 = make_float2(0.f, 0.f);

#pragma unroll 4
    for (int dd = 0; dd < 64; dd += 4) {
      float2 w0 = *(const float2*)(Wd + (size_t)(dd + 0) * A);
      float2 w1 = *(const float2*)(Wd + (size_t)(dd + 1) * A);
      float2 w2 = *(const float2*)(Wd + (size_t)(dd + 2) * A);
      float2 w3 = *(const float2*)(Wd + (size_t)(dd + 3) * A);
      float4 x0 = *(const float4*)(Xr + (size_t)0 * D + dd);
      float4 x1 = *(const float4*)(Xr + (size_t)1 * D + dd);
      a0.x = fmaf(x0.x, w0.x, a0.x);  a0.y = fmaf(x0.x, w0.y, a0.y);
      a0.x = fmaf(x0.y, w1.x, a0.x);  a0.y = fmaf(x0.y, w1.y, a0.y);
      a0.x = fmaf(x0.z, w2.x, a0.x);  a0.y = fmaf(x0.z, w2.y, a0.y);
      a0.x = fmaf(x0.w, w3.x, a0.x);  a0.y = fmaf(x0.w, w3.y, a0.y);
      a1.x = fmaf(x1.x, w0.x, a1.x);  a1.y = fmaf(x1.x, w0.y, a1.y);
      a1.x = fmaf(x1.y, w1.x, a1.x);  a1.y = fmaf(x1.y, w1.y, a1.y);
      a1.x = fmaf(x1.z, w2.x, a1.x);  a1.y = fmaf(x1.z, w2.y, a1.y);
      a1.x = fmaf(x1.w, w3.x, a1.x);  a1.y = fmaf(x1.w, w3.y, a1.y);
    }

    *(float2*)&ps[0][g][ap] = a0;
    *(float2*)&ps[1][g][ap] = a1;
    __syncthreads();

    if (tid < 128) {
      int j  = tid >> 6;            // 0..1
      int a2 = (tid & 63) * 2;
      float2 s0 = *(const float2*)&ps[j][0][a2];
      float2 s1 = *(const float2*)&ps[j][1][a2];
      float2 s2 = *(const float2*)&ps[j][2][a2];
      float2 s3 = *(const float2*)&ps[j][3][a2];
      float2 s4 = *(const float2*)&ps[j][4][a2];
      float2 s5 = *(const float2*)&ps[j][5][a2];
      float2 s6 = *(const float2*)&ps[j][6][a2];
      float2 s7 = *(const float2*)&ps[j][7][a2];
      float2 bz = *(const float2*)(bq + a2);
      float2 ev;
      ev.x = __builtin_amdgcn_exp2f(
          ((((s0.x + s1.x) + (s2.x + s3.x)) + ((s4.x + s5.x) + (s6.x + s7.x))) + bz.x) * TWO_LOG2E);
      ev.y = __builtin_amdgcn_exp2f(
          ((((s0.y + s1.y) + (s2.y + s3.y)) + ((s4.y + s5.y) + (s6.y + s7.y))) + bz.y) * TWO_LOG2E);
      *(float2*)(Eq + (size_t)(r0 + j) * A + a2) = ev;
    }
  }

  cg::this_grid().sync();   // Eq + EkT complete, visible device-wide

  // ------------------- Phase 2: score + softmax (2 q rows) -------------------
  {
    int v0  = (tid & 63) * 2 + (tid >> 6) * 128;  // wave-contiguous float2
    int xcd = blockIdx.x & 7;
    int grp = blockIdx.x >> 3;           // 0..63
    int b   = xcd & 3;
    int pair = (xcd >> 2) * 64 + grp;    // 0..127
    int r0  = b * TQ + pair * 2;

    const float* eqA = Eq + (size_t)r0 * A;
    const float* eqB = eqA + A;

    float sumV = 0.f;
#pragma unroll 16
    for (int i = 0; i < A; ++i) sumV += attn_v[i];

    const float* ekb = EkT + (size_t)b * A * TV + v0;
    float2 tA = make_float2(0.f, 0.f);
    float2 tB = make_float2(0.f, 0.f);

    float2 p00 = *(const float2*)(ekb + (size_t)0 * TV);
    float2 p01 = *(const float2*)(ekb + (size_t)1 * TV);
    float2 p02 = *(const float2*)(ekb + (size_t)2 * TV);
    float2 p03 = *(const float2*)(ekb + (size_t)3 * TV);
    float2 p10 = *(const float2*)(ekb + (size_t)4 * TV);
    float2 p11 = *(const float2*)(ekb + (size_t)5 * TV);
    float2 p12 = *(const float2*)(ekb + (size_t)6 * TV);
    float2 p13 = *(const float2*)(ekb + (size_t)7 * TV);

    for (int i = 0; i < A; i += 8) {
      {
        float av0 = attn_v[i + 0], av1 = attn_v[i + 1];
        float av2 = attn_v[i + 2], av3 = attn_v[i + 3];
        float qa0 = eqA[i + 0], qa1 = eqA[i + 1], qa2 = eqA[i + 2], qa3 = eqA[i + 3];
        float qb0 = eqB[i + 0], qb1 = eqB[i + 1], qb2 = eqB[i + 2], qb3 = eqB[i + 3];

        tA.x = fmaf(av0, __builtin_amdgcn_rcpf(fmaf(p00.x, qa0, 1.f)), tA.x);
        tA.y = fmaf(av0, __builtin_amdgcn_rcpf(fmaf(p00.y, qa0, 1.f)), tA.y);
        tB.x = fmaf(av0, __builtin_amdgcn_rcpf(fmaf(p00.x, qb0, 1.f)), tB.x);
        tB.y = fmaf(av0, __builtin_amdgcn_rcpf(fmaf(p00.y, qb0, 1.f)), tB.y);

        tA.x = fmaf(av1, __builtin_amdgcn_rcpf(fmaf(p01.x, qa1, 1.f)), tA.x);
        tA.y = fmaf(av1, __builtin_amdgcn_rcpf(fmaf(p01.y, qa1, 1.f)), tA.y);
        tB.x = fmaf(av1, __builtin_amdgcn_rcpf(fmaf(p01.x, qb1, 1.f)), tB.x);
        tB.y = fmaf(av1, __builtin_amdgcn_rcpf(fmaf(p01.y, qb1, 1.f)), tB.y);

        tA.x = fmaf(av2, __builtin_amdgcn_rcpf(fmaf(p02.x, qa2, 1.f)), tA.x);
        tA.y = fmaf(av2, __builtin_amdgcn_rcpf(fmaf(p02.y, qa2, 1.f)), tA.y);
        tB.x = fmaf(av2, __builtin_amdgcn_rcpf(fmaf(p02.x, qb2, 1.f)), tB.x);
        tB.y = fmaf(av2, __builtin_amdgcn_rcpf(fmaf(p02.y, qb2, 1.f)), tB.y);

        tA.x = fmaf(av3, __builtin_amdgcn_rcpf(fmaf(p03.x, qa3, 1.f)), tA.x);
        tA.y = fmaf(av3, __builtin_amdgcn_rcpf(fmaf(p03.y, qa3, 1.f)), tA.y);
        tB.x = fmaf(av3, __builtin_amdgcn_rcpf(fmaf(p03.x, qb3, 1.f)), tB.x);
        tB.y = fmaf(av3, __builtin_amdgcn_rcpf(fmaf(p03.y, qb3, 1.f)), tB.y);
      }
      p00 = *(const float2*)(ekb + (size_t)(i + 8) * TV);
      p01 = *(const float2*)(ekb + (size_t)(i + 9) * TV);
      p02 = *(const float2*)(ekb + (size_t)(i + 10) * TV);
      p03 = *(const float2*)(ekb + (size_t)(i + 11) * TV);

      {
        float av0 = attn_v[i + 4], av1 = attn_v[i + 5];
        float av2 = attn_v[i + 6], av3 = attn_v[i + 7];
        float qa0 = eqA[i + 4], qa1 = eqA[i + 5], qa2 = eqA[i + 6], qa3 = eqA[i + 7];
        float qb0 = eqB[i + 4], qb1 = eqB[i + 5], qb2 = eqB[i + 6], qb3 = eqB[i + 7];

        tA.x = fmaf(av0, __builtin_amdgcn_rcpf(fmaf(p10.x, qa0, 1.f)), tA.x);
        tA.y = fmaf(av0, __builtin_amdgcn_rcpf(fmaf(p10.y, qa0, 1.f)), tA.y);
        tB.x = fmaf(av0, __builtin_amdgcn_rcpf(fmaf(p10.x, qb0, 1.f)), tB.x);
        tB.y = fmaf(av0, __builtin_amdgcn_rcpf(fmaf(p10.y, qb0, 1.f)), tB.y);

        tA.x = fmaf(av1, __builtin_amdgcn_rcpf(fmaf(p11.x, qa1, 1.f)), tA.x);
        tA.y = fmaf(av1, __builtin_amdgcn_rcpf(fmaf(p11.y, qa1, 1.f)), tA.y);
        tB.x = fmaf(av1, __builtin_amdgcn_rcpf(fmaf(p11.x, qb1, 1.f)), tB.x);
        tB.y = fmaf(av1, __builtin_amdgcn_rcpf(fmaf(p11.y, qb1, 1.f)), tB.y);

        tA.x = fmaf(av2, __builtin_amdgcn_rcpf(fmaf(p12.x, qa2, 1.f)), tA.x);
        tA.y = fmaf(av2, __builtin_amdgcn_rcpf(fmaf(p12.y, qa2, 1.f)), tA.y);
        tB.x = fmaf(av2, __builtin_amdgcn_rcpf(fmaf(p12.x, qb2, 1.f)), tB.x);
        tB.y = fmaf(av2, __builtin_amdgcn_rcpf(fmaf(p12.y, qb2, 1.f)), tB.y);

        tA.x = fmaf(av3, __builtin_amdgcn_rcpf(fmaf(p13.x, qa3, 1.f)), tA.x);
        tA.y = fmaf(av3, __builtin_amdgcn_rcpf(fmaf(p13.y, qa3, 1.f)), tA.y);
        tB.x = fmaf(av3, __builtin_amdgcn_rcpf(fmaf(p13.x, qb3, 1.f)), tB.x);
        tB.y = fmaf(av3, __builtin_amdgcn_rcpf(fmaf(p13.y, qb3, 1.f)), tB.y);
      }
      p10 = *(const float2*)(ekb + (size_t)(i + 12) * TV);
      p11 = *(const float2*)(ekb + (size_t)(i + 13) * TV);
      p12 = *(const float2*)(ekb + (size_t)(i + 14) * TV);
      p13 = *(const float2*)(ekb + (size_t)(i + 15) * TV);
    }

    int2 mk = *(const int2*)(mask + b * TV + v0);
    float mkx = (1.f - (float)mk.x) * NEG_BIG_F;
    float mky = (1.f - (float)mk.y) * NEG_BIG_F;
    float2 sA, sB;
    sA.x = sumV - 2.f * tA.x + mkx;
    sA.y = sumV - 2.f * tA.y + mky;
    sB.x = sumV - 2.f * tB.x + mkx;
    sB.y = sumV - 2.f * tB.y + mky;

    float mA = fmaxf(sA.x, sA.y);
    float mB = fmaxf(sB.x, sB.y);
    for (int off = 32; off > 0; off >>= 1) {
      mA = fmaxf(mA, __shfl_down(mA, off, 64));
      mB = fmaxf(mB, __shfl_down(mB, off, 64));
    }
    int w = tid >> 6;
    if ((tid & 63) == 0) { redA[w] = mA; redB[w] = mB; }
    __syncthreads();
    if (tid == 0) {
      float a = redA[0], bm = redB[0];
#pragma unroll
      for (int i = 1; i < 8; ++i) { a = fmaxf(a, redA[i]); bm = fmaxf(bm, redB[i]); }
      bc[0] = a; bc[1] = bm;
    }
    __syncthreads();
    float MA = bc[0], MB = bc[1];

    float2 eAv, eBv;
    eAv.x = __builtin_amdgcn_exp2f((sA.x - MA) * LOG2E);
    eAv.y = __builtin_amdgcn_exp2f((sA.y - MA) * LOG2E);
    eBv.x = __builtin_amdgcn_exp2f((sB.x - MB) * LOG2E);
    eBv.y = __builtin_amdgcn_exp2f((sB.y - MB) * LOG2E);
    float lA = eAv.x + eAv.y;
    float lB = eBv.x + eBv.y;
    for (int off = 32; off > 0; off >>= 1) {
      lA += __shfl_down(lA, off, 64);
      lB += __shfl_down(lB, off, 64);
    }
    __syncthreads();   // protect red[] before rewrite
    if ((tid & 63) == 0) { redA[w] = lA; redB[w] = lB; }
    __syncthreads();
    if (tid == 0) {
      float a = 0.f, bs = 0.f;
#pragma unroll
      for (int i = 0; i < 8; ++i) { a += redA[i]; bs += redB[i]; }
      bc[2] = a; bc[3] = bs;
    }
    __syncthreads();
    float iA = 1.f / bc[2];
    float iB = 1.f / bc[3];

    *(float2*)(attn + (size_t)r0 * TV + v0) =
        make_float2(eAv.x * iA, eAv.y * iA);
    *(float2*)(attn + (size_t)(r0 + 1) * TV + v0) =
        make_float2(eBv.x * iB, eBv.y * iB);
  }

  cg::this_grid().sync();   // attn complete, visible device-wide

  // ------------------- Phase 3: pv -------------------
  {
    int gsl = blockIdx.x & 15;         // (b, dt) slice group
    int b   = gsl & 3;
    int dt  = gsl >> 2;                // 0..3, d-slice of 128
    int qt  = blockIdx.x >> 4;         // 0..31
    int q0  = b * TQ + qt * 8;         // global row (b*TQ + q)
    int w    = tid >> 6;               // wave 0..7 -> v range [w*128, +128)
    int lane = tid & 63;
    int col  = lane & 31;              // float4 d-column
    int qh   = lane >> 5;              // 0..1 -> q rows qh*4 .. qh*4+3
    int d0 = dt * 128 + col * 4;

    // stage attn tile: 8 rows x 1024 v (float4, coalesced)
    {
      const float4* src = (const float4*)(attn + (size_t)q0 * TV);
      float4* dst = (float4*)lds;
      for (int i = tid; i < 8 * 256; i += 512) dst[i] = src[i];
    }
    __syncthreads();

    float4 acc[4];
#pragma unroll
    for (int j = 0; j < 4; ++j) acc[j] = make_float4(0.f, 0.f, 0.f, 0.f);

    int vbase = w * 128;
    const float* Xb = inp + ((size_t)b * TV + vbase) * D + d0;
    const float* arow = &lds[(qh * 4) * 1024 + vbase];  // 4 rows, stride 1024

    float4 xc0 = *(const float4*)(Xb + (size_t)0 * D);
    float4 xc1 = *(const float4*)(Xb + (size_t)1 * D);
    float4 xc2 = *(const float4*)(Xb + (size_t)2 * D);
    float4 xc3 = *(const float4*)(Xb + (size_t)3 * D);

    for (int vi = 0; vi < 128; vi += 4) {
      float4 xn0, xn1, xn2, xn3;
      if (vi < 124) {
        const float* Xn = Xb + (size_t)(vi + 4) * D;
        xn0 = *(const float4*)(Xn + (size_t)0 * D);
        xn1 = *(const float4*)(Xn + (size_t)1 * D);
        xn2 = *(const float4*)(Xn + (size_t)2 * D);
        xn3 = *(const float4*)(Xn + (size_t)3 * D);
      }
#pragma unroll
      for (int j = 0; j < 4; ++j) {
        float4 av = *(const float4*)(arow + j * 1024 + vi);  // 2-addr bcast
        acc[j].x = fmaf(av.x, xc0.x, acc[j].x);
        acc[j].y = fmaf(av.x, xc0.y, acc[j].y);
        acc[j].z = fmaf(av.x, xc0.z, acc[j].z);
        acc[j].w = fmaf(av.x, xc0.w, acc[j].w);
        acc[j].x = fmaf(av.y, xc1.x, acc[j].x);
        acc[j].y = fmaf(av.y, xc1.y, acc[j].y);
        acc[j].z = fmaf(av.y, xc1.z, acc[j].z);
        acc[j].w = fmaf(av.y, xc1.w, acc[j].w);
        acc[j].x = fmaf(av.z, xc2.x, acc[j].x);
        acc[j].y = fmaf(av.z, xc2.y, acc[j].y);
        acc[j].z = fmaf(av.z, xc2.z, acc[j].z);
        acc[j].w = fmaf(av.z, xc2.w, acc[j].w);
        acc[j].x = fmaf(av.w, xc3.x, acc[j].x);
        acc[j].y = fmaf(av.w, xc3.y, acc[j].y);
        acc[j].z = fmaf(av.w, xc3.z, acc[j].z);
        acc[j].w = fmaf(av.w, xc3.w, acc[j].w);
      }
      xc0 = xn0; xc1 = xn1; xc2 = xn2; xc3 = xn3;
    }

    __syncthreads();   // everyone done READING the attn tile

    {
      float4* pat = (float4*)lds + (size_t)w * 256;
#pragma unroll
      for (int j = 0; j < 4; ++j)
        pat[(qh * 4 + j) * 32 + col] = acc[j];
    }
    __syncthreads();

    if (tid < 256) {
      int row = tid >> 5;            // 0..7
      int c   = tid & 31;            // 0..31
      const float4* p = (const float4*)lds + tid;  // == row*32 + c
      float4 r = p[0];
#pragma unroll
      for (int i = 1; i < 8; ++i) {
        float4 t = p[(size_t)i * 256];
        r.x += t.x; r.y += t.y; r.z += t.z; r.w += t.w;
      }
      *(float4*)(out + (size_t)(q0 + row) * D + dt * 128 + c * 4) = r;
    }
  }
}

// ===========================================================================
// Fallback 3-kernel path (used only if cooperative launch is unavailable).
// ===========================================================================
__global__ __launch_bounds__(512, 4) void proj_exp_kernel(
    const float* __restrict__ ctx, const float* __restrict__ inp,
    const float* __restrict__ Wq, const float* __restrict__ bq,
    const float* __restrict__ Wk, const float* __restrict__ bk,
    float* __restrict__ Eq, float* __restrict__ EkT) {
  __shared__ float ps[8][8][A];
  __shared__ float es[A][9];

  bool isQ = blockIdx.x < QBLK;
  const float* X; const float* W; const float* bias; int r0;
  if (isQ) { X = ctx; W = Wq; bias = bq; r0 = blockIdx.x * 8; }
  else     { X = inp; W = Wk; bias = bk; r0 = (blockIdx.x - QBLK) * 8; }

  int tid = threadIdx.x;
  int ap = (tid & 63) * 2;
  int g  = tid >> 6;

  int dbase = __builtin_amdgcn_readfirstlane(g * 64);
  const float* Xr = X + (size_t)r0 * D + dbase;
  const float* Wd = W + (size_t)dbase * A + ap;

  float2 acc[8];
#pragma unroll
  for (int j = 0; j < 8; ++j) acc[j] = make_float2(0.f, 0.f);

#pragma unroll 2
  for (int dd = 0; dd < 64; dd += 4) {
    float2 w0 = *(const float2*)(Wd + (size_t)(dd + 0) * A);
    float2 w1 = *(const float2*)(Wd + (size_t)(dd + 1) * A);
    float2 w2 = *(const float2*)(Wd + (size_t)(dd + 2) * A);
    float2 w3 = *(const float2*)(Wd + (size_t)(dd + 3) * A);
    float4 x[8];
#pragma unroll
    for (int j = 0; j < 8; ++j)
      x[j] = *(const float4*)(Xr + (size_t)j * D + dd);
#pragma unroll
    for (int j = 0; j < 8; ++j) {
      acc[j].x = fmaf(x[j].x, w0.x, acc[j].x);
      acc[j].y = fmaf(x[j].x, w0.y, acc[j].y);
      acc[j].x = fmaf(x[j].y, w1.x, acc[j].x);
      acc[j].y = fmaf(x[j].y, w1.y, acc[j].y);
      acc[j].x = fmaf(x[j].z, w2.x, acc[j].x);
      acc[j].y = fmaf(x[j].z, w2.y, acc[j].y);
      acc[j].x = fmaf(x[j].w, w3.x, acc[j].x);
      acc[j].y = fmaf(x[j].w, w3.y, acc[j].y);
    }
  }

#pragma unroll
  for (int j = 0; j < 8; ++j)
    *(float2*)&ps[j][g][ap] = acc[j];
  __syncthreads();

  int j  = tid >> 6;
  int a2 = (tid & 63) * 2;
  float2 s0 = *(const float2*)&ps[j][0][a2];
  float2 s1 = *(const float2*)&ps[j][1][a2];
  float2 s2 = *(const float2*)&ps[j][2][a2];
  float2 s3 = *(const float2*)&ps[j][3][a2];
  float2 s4 = *(const float2*)&ps[j][4][a2];
  float2 s5 = *(const float2*)&ps[j][5][a2];
  float2 s6 = *(const float2*)&ps[j][6][a2];
  float2 s7 = *(const float2*)&ps[j][7][a2];
  float2 bz = *(const float2*)(bias + a2);
  float2 ev;
  ev.x = __builtin_amdgcn_exp2f(
      ((((s0.x + s1.x) + (s2.x + s3.x)) + ((s4.x + s5.x) + (s6.x + s7.x))) + bz.x) * TWO_LOG2E);
  ev.y = __builtin_amdgcn_exp2f(
      ((((s0.y + s1.y) + (s2.y + s3.y)) + ((s4.y + s5.y) + (s6.y + s7.y))) + bz.y) * TWO_LOG2E);

  if (isQ) {
    *(float2*)(Eq + (size_t)(r0 + j) * A + a2) = ev;
  } else {
    es[a2 + 0][j] = ev.x;
    es[a2 + 1][j] = ev.y;
    __syncthreads();
    int b  = r0 >> 10;
    int v0 = r0 & (TV - 1);
    for (int i = tid; i < A * 8; i += 512) {
      int aa = i >> 3, jj = i & 7;
      EkT[((size_t)b * A + aa) * TV + v0 + jj] = es[aa][jj];
    }
  }
}

__global__ __launch_bounds__(512, 4) void score_softmax_kernel(
    const float* __restrict__ Eq, const float* __restrict__ EkT,
    const float* __restrict__ attn_v, const int* __restrict__ mask,
    float* __restrict__ attn) {
  __shared__ float redA[8], redB[8];
  __shared__ float bc[4];

  int tid = threadIdx.x;
  int v0  = (tid & 63) * 2 + (tid >> 6) * 128;
  int xcd = blockIdx.x & 7;
  int grp = blockIdx.x >> 3;
  int b   = xcd & 3;
  int pair = (xcd >> 2) * 64 + grp;
  int r0  = b * TQ + pair * 2;

  const float* eqA = Eq + (size_t)r0 * A;
  const float* eqB = eqA + A;

  float sumV = 0.f;
#pragma unroll 16
  for (int i = 0; i < A; ++i) sumV += attn_v[i];

  const float* ekb = EkT + (size_t)b * A * TV + v0;
  float2 tA = make_float2(0.f, 0.f);
  float2 tB = make_float2(0.f, 0.f);

  float2 c0 = *(const float2*)(ekb + (size_t)0 * TV);
  float2 c1 = *(const float2*)(ekb + (size_t)1 * TV);
  float2 c2 = *(const float2*)(ekb + (size_t)2 * TV);
  float2 c3 = *(const float2*)(ekb + (size_t)3 * TV);

  for (int i = 0; i < A; i += 4) {
    float2 n0, n1, n2, n3;
    if (i < A - 4) {
      n0 = *(const float2*)(ekb + (size_t)(i + 4) * TV);
      n1 = *(const float2*)(ekb + (size_t)(i + 5) * TV);
      n2 = *(const float2*)(ekb + (size_t)(i + 6) * TV);
      n3 = *(const float2*)(ekb + (size_t)(i + 7) * TV);
    }
    float av0 = attn_v[i + 0], av1 = attn_v[i + 1];
    float av2 = attn_v[i + 2], av3 = attn_v[i + 3];
    float qa0 = eqA[i + 0], qa1 = eqA[i + 1], qa2 = eqA[i + 2], qa3 = eqA[i + 3];
    float qb0 = eqB[i + 0], qb1 = eqB[i + 1], qb2 = eqB[i + 2], qb3 = eqB[i + 3];

    tA.x = fmaf(av0, __builtin_amdgcn_rcpf(fmaf(c0.x, qa0, 1.f)), tA.x);
    tA.y = fmaf(av0, __builtin_amdgcn_rcpf(fmaf(c0.y, qa0, 1.f)), tA.y);
    tB.x = fmaf(av0, __builtin_amdgcn_rcpf(fmaf(c0.x, qb0, 1.f)), tB.x);
    tB.y = fmaf(av0, __builtin_amdgcn_rcpf(fmaf(c0.y, qb0, 1.f)), tB.y);

    tA.x = fmaf(av1, __builtin_amdgcn_rcpf(fmaf(c1.x, qa1, 1.f)), tA.x);
    tA.y = fmaf(av1, __builtin_amdgcn_rcpf(fmaf(c1.y, qa1, 1.f)), tA.y);
    tB.x = fmaf(av1, __builtin_amdgcn_rcpf(fmaf(c1.x, qb1, 1.f)), tB.x);
    tB.y = fmaf(av1, __builtin_amdgcn_rcpf(fmaf(c1.y, qb1, 1.f)), tB.y);

    tA.x = fmaf(av2, __builtin_amdgcn_rcpf(fmaf(c2.x, qa2, 1.f)), tA.x);
    tA.y = fmaf(av2, __builtin_amdgcn_rcpf(fmaf(c2.y, qa2, 1.f)), tA.y);
    tB.x = fmaf(av2, __builtin_amdgcn_rcpf(fmaf(c2.x, qb2, 1.f)), tB.x);
    tB.y = fmaf(av2, __builtin_amdgcn_rcpf(fmaf(c2.y, qb2, 1.f)), tB.y);

    tA.x = fmaf(av3, __builtin_amdgcn_rcpf(fmaf(c3.x, qa3, 1.f)), tA.x);
    tA.y = fmaf(av3, __builtin_amdgcn_rcpf(fmaf(c3.y, qa3, 1.f)), tA.y);
    tB.x = fmaf(av3, __builtin_amdgcn_rcpf(fmaf(c3.x, qb3, 1.f)), tB.x);
    tB.y = fmaf(av3, __builtin_amdgcn_rcpf(fmaf(c3.y, qb3, 1.f)), tB.y);

    c0 = n0; c1 = n1; c2 = n2; c3 = n3;
  }

  int2 mk = *(const int2*)(mask + b * TV + v0);
  float mkx = (1.f - (float)mk.x) * NEG_BIG_F;
  float mky = (1.f - (float)mk.y) * NEG_BIG_F;
  float2 sA, sB;
  sA.x = sumV - 2.f * tA.x + mkx;
  sA.y = sumV - 2.f * tA.y + mky;
  sB.x = sumV - 2.f * tB.x + mkx;
  sB.y = sumV - 2.f * tB.y + mky;

  float mA = fmaxf(sA.x, sA.y);
  float mB = fmaxf(sB.x, sB.y);
  for (int off = 32; off > 0; off >>= 1) {
    mA = fmaxf(mA, __shfl_down(mA, off, 64));
    mB = fmaxf(mB, __shfl_down(mB, off, 64));
  }
  int w = tid >> 6;
  if ((tid & 63) == 0) { redA[w] = mA; redB[w] = mB; }
  __syncthreads();
  if (tid == 0) {
    float a = redA[0], bm = redB[0];
#pragma unroll
    for (int i = 1; i < 8; ++i) { a = fmaxf(a, redA[i]); bm = fmaxf(bm, redB[i]); }
    bc[0] = a; bc[1] = bm;
  }
  __syncthreads();
  float MA = bc[0], MB = bc[1];

  float2 eAv, eBv;
  eAv.x = __builtin_amdgcn_exp2f((sA.x - MA) * LOG2E);
  eAv.y = __builtin_amdgcn_exp2f((sA.y - MA) * LOG2E);
  eBv.x = __builtin_amdgcn_exp2f((sB.x - MB) * LOG2E);
  eBv.y = __builtin_amdgcn_exp2f((sB.y - MB) * LOG2E);
  float lA = eAv.x + eAv.y;
  float lB = eBv.x + eBv.y;
  for (int off = 32; off > 0; off >>= 1) {
    lA += __shfl_down(lA, off, 64);
    lB += __shfl_down(lB, off, 64);
  }
  __syncthreads();
  if ((tid & 63) == 0) { redA[w] = lA; redB[w] = lB; }
  __syncthreads();
  if (tid == 0) {
    float a = 0.f, bs = 0.f;
#pragma unroll
    for (int i = 0; i < 8; ++i) { a += redA[i]; bs += redB[i]; }
    bc[2] = a; bc[3] = bs;
  }
  __syncthreads();
  float iA = 1.f / bc[2];
  float iB = 1.f / bc[3];

  *(float2*)(attn + (size_t)r0 * TV + v0) =
      make_float2(eAv.x * iA, eAv.y * iA);
  *(float2*)(attn + (size_t)(r0 + 1) * TV + v0) =
      make_float2(eBv.x * iB, eBv.y * iB);
}

__global__ __launch_bounds__(512, 4) void pv_kernel(
    const float* __restrict__ attn, const float* __restrict__ X,
    float* __restrict__ out) {
  __shared__ float lds[8 * 1024];
  int gsl = blockIdx.x & 15;
  int b   = gsl & 3;
  int dt  = gsl >> 2;
  int qt  = blockIdx.x >> 4;
  int q0  = b * TQ + qt * 8;
  int tid  = threadIdx.x;
  int w    = tid >> 6;
  int lane = tid & 63;
  int col  = lane & 31;
  int qh   = lane >> 5;
  int d0 = dt * 128 + col * 4;

  {
    const float4* src = (const float4*)(attn + (size_t)q0 * TV);
    float4* dst = (float4*)lds;
    for (int i = tid; i < 8 * 256; i += 512) dst[i] = src[i];
  }
  __syncthreads();

  float4 acc[4];
#pragma unroll
  for (int j = 0; j < 4; ++j) acc[j] = make_float4(0.f, 0.f, 0.f, 0.f);

  int vbase = w * 128;
  const float* Xb = X + ((size_t)b * TV + vbase) * D + d0;
  const float* arow = &lds[(qh * 4) * 1024 + vbase];

  float4 xc0 = *(const float4*)(Xb + (size_t)0 * D);
  float4 xc1 = *(const float4*)(Xb + (size_t)1 * D);
  float4 xc2 = *(const float4*)(Xb + (size_t)2 * D);
  float4 xc3 = *(const float4*)(Xb + (size_t)3 * D);

  for (int vi = 0; vi < 128; vi += 4) {
    float4 xn0, xn1, xn2, xn3;
    if (vi < 124) {
      const float* Xn = Xb + (size_t)(vi + 4) * D;
      xn0 = *(const float4*)(Xn + (size_t)0 * D);
      xn1 = *(const float4*)(Xn + (size_t)1 * D);
      xn2 = *(const float4*)(Xn + (size_t)2 * D);
      xn3 = *(const float4*)(Xn + (size_t)3 * D);
    }
#pragma unroll
    for (int j = 0; j < 4; ++j) {
      float4 av = *(const float4*)(arow + j * 1024 + vi);
      acc[j].x = fmaf(av.x, xc0.x, acc[j].x);
      acc[j].y = fmaf(av.x, xc0.y, acc[j].y);
      acc[j].z = fmaf(av.x, xc0.z, acc[j].z);
      acc[j].w = fmaf(av.x, xc0.w, acc[j].w);
      acc[j].x = fmaf(av.y, xc1.x, acc[j].x);
      acc[j].y = fmaf(av.y, xc1.y, acc[j].y);
      acc[j].z = fmaf(av.y, xc1.z, acc[j].z);
      acc[j].w = fmaf(av.y, xc1.w, acc[j].w);
      acc[j].x = fmaf(av.z, xc2.x, acc[j].x);
      acc[j].y = fmaf(av.z, xc2.y, acc[j].y);
      acc[j].z = fmaf(av.z, xc2.z, acc[j].z);
      acc[j].w = fmaf(av.z, xc2.w, acc[j].w);
      acc[j].x = fmaf(av.w, xc3.x, acc[j].x);
      acc[j].y = fmaf(av.w, xc3.y, acc[j].y);
      acc[j].z = fmaf(av.w, xc3.z, acc[j].z);
      acc[j].w = fmaf(av.w, xc3.w, acc[j].w);
    }
    xc0 = xn0; xc1 = xn1; xc2 = xn2; xc3 = xn3;
  }

  __syncthreads();

  {
    float4* pat = (float4*)lds + (size_t)w * 256;
#pragma unroll
    for (int j = 0; j < 4; ++j)
      pat[(qh * 4 + j) * 32 + col] = acc[j];
  }
  __syncthreads();

  if (tid < 256) {
    int row = tid >> 5;
    int c   = tid & 31;
    const float4* p = (const float4*)lds + tid;
    float4 r = p[0];
#pragma unroll
    for (int i = 1; i < 8; ++i) {
      float4 t = p[(size_t)i * 256];
      r.x += t.x; r.y += t.y; r.z += t.z; r.w += t.w;
    }
    *(float4*)(out + (size_t)(q0 + row) * D + dt * 128 + c * 4) = r;
  }
}

extern "C" void kernel_launch(void* const* d_in, const int* in_sizes, int n_in,
                              void* d_out, int out_size, void* d_ws, size_t ws_size,
                              hipStream_t stream) {
  const float* inputs  = (const float*)d_in[0];  // [B,TV,D]
  const float* context = (const float*)d_in[1];  // [B,TQ,D]
  const int*   mask    = (const int*)d_in[2];    // [B,TV]
  const float* Wk      = (const float*)d_in[3];  // [D,A]
  const float* bk      = (const float*)d_in[4];  // [A]
  const float* Wq      = (const float*)d_in[5];  // [D,A]
  const float* bq      = (const float*)d_in[6];  // [A]
  const float* attn_v  = (const float*)d_in[7];  // [A]
  float* out = (float*)d_out;                    // [B,TQ,D]

  // Workspace layout (fp32): Eq | EkT | attn  = 0.5MB + 2MB + 4MB
  float* Eq   = (float*)d_ws;             // [B*TQ, A]
  float* EkT  = Eq + B * TQ * A;          // [B, A, TV]  (transposed!)
  float* attn = EkT + (size_t)B * A * TV; // [B*TQ, TV]

  void* args[] = {(void*)&context, (void*)&inputs,
                  (void*)&Wq, (void*)&bq, (void*)&Wk, (void*)&bk,
                  (void*)&attn_v, (void*)&mask,
                  (void*)&Eq, (void*)&EkT, (void*)&attn, (void*)&out};
  hipError_t err = hipLaunchCooperativeKernel(
      (const void*)fused_kernel, dim3(512), dim3(512), args, 0, stream);

  if (err != hipSuccess) {
    // Fallback: original 3-kernel pipeline.
    proj_exp_kernel<<<QBLK + KBLK, 512, 0, stream>>>(context, inputs, Wq, bq,
                                                     Wk, bk, Eq, EkT);
    score_softmax_kernel<<<B * TQ / 2, 512, 0, stream>>>(Eq, EkT, attn_v, mask,
                                                         attn);
    pv_kernel<<<512, 512, 0, stream>>>(attn, inputs, out);
  }
}

// Round 3
// 146.755 us; speedup vs baseline: 1.8695x; 1.8695x over previous
//
#include <hip/hip_runtime.h>
#include <math.h>

// Problem sizes (fixed by the reference)
#define B   4
#define TQ  256
#define TV  1024
#define D   512
#define A   128

#define LOG2E     1.4426950408889634f
#define TWO_LOG2E 2.8853900817779268f
#define NEG_BIG_F (-1e9f)

#define QBLK (B * TQ / 8)   // 128 q-projection blocks
#define KBLK (B * TV / 8)   // 512 k-projection blocks

// ---------------------------------------------------------------------------
// Fused projection + exp(2x) for BOTH q and k.  (round-12 structure, proven)
//   q path: Eq[r, a]     = exp(2*(ctx[r,:]@Wq[:,a] + bq[a]))   [row-major]
//   k path: EkT[b, a, v] = exp(2*(inp[r,:]@Wk[:,a] + bk[a]))   [TRANSPOSED]
// 512 threads (8 waves), d-split 8-way per wave (64 d each). All 64 lanes of
// a wave share X addresses -> s_load_dwordx4. Lane owns an a-pair x 8 rows.
// ---------------------------------------------------------------------------
__global__ __launch_bounds__(512, 4) void proj_exp_kernel(
    const float* __restrict__ ctx, const float* __restrict__ inp,
    const float* __restrict__ Wq, const float* __restrict__ bq,
    const float* __restrict__ Wk, const float* __restrict__ bk,
    float* __restrict__ Eq, float* __restrict__ EkT) {
  __shared__ float ps[8][8][A];     // 32 KB (row j, wave, a)
  __shared__ float es[A][9];        // 4.6 KB (transpose staging, +1 pad)

  bool isQ = blockIdx.x < QBLK;
  const float* X; const float* W; const float* bias; int r0;
  if (isQ) { X = ctx; W = Wq; bias = bq; r0 = blockIdx.x * 8; }
  else     { X = inp; W = Wk; bias = bk; r0 = (blockIdx.x - QBLK) * 8; }

  int tid = threadIdx.x;
  int ap = (tid & 63) * 2;      // a-pair base: 64 lanes cover a = 0..127
  int g  = tid >> 6;            // wave id 0..7  (wave-uniform)

  int dbase = __builtin_amdgcn_readfirstlane(g * 64);
  const float* Xr = X + (size_t)r0 * D + dbase;   // wave-uniform base
  const float* Wd = W + (size_t)dbase * A + ap;

  float2 acc[8];
#pragma unroll
  for (int j = 0; j < 8; ++j) acc[j] = make_float2(0.f, 0.f);

#pragma unroll 2
  for (int dd = 0; dd < 64; dd += 4) {
    float2 w0 = *(const float2*)(Wd + (size_t)(dd + 0) * A);
    float2 w1 = *(const float2*)(Wd + (size_t)(dd + 1) * A);
    float2 w2 = *(const float2*)(Wd + (size_t)(dd + 2) * A);
    float2 w3 = *(const float2*)(Wd + (size_t)(dd + 3) * A);
    float4 x[8];
#pragma unroll
    for (int j = 0; j < 8; ++j)
      x[j] = *(const float4*)(Xr + (size_t)j * D + dd);   // scalar s_load
#pragma unroll
    for (int j = 0; j < 8; ++j) {
      acc[j].x = fmaf(x[j].x, w0.x, acc[j].x);
      acc[j].y = fmaf(x[j].x, w0.y, acc[j].y);
      acc[j].x = fmaf(x[j].y, w1.x, acc[j].x);
      acc[j].y = fmaf(x[j].y, w1.y, acc[j].y);
      acc[j].x = fmaf(x[j].z, w2.x, acc[j].x);
      acc[j].y = fmaf(x[j].z, w2.y, acc[j].y);
      acc[j].x = fmaf(x[j].w, w3.x, acc[j].x);
      acc[j].y = fmaf(x[j].w, w3.y, acc[j].y);
    }
  }

#pragma unroll
  for (int j = 0; j < 8; ++j)
    *(float2*)&ps[j][g][ap] = acc[j];
  __syncthreads();

  // reduce 8 wave-partials: row j = tid>>6, a-pair per lane
  int j  = tid >> 6;            // 0..7
  int a2 = (tid & 63) * 2;
  float2 s0 = *(const float2*)&ps[j][0][a2];
  float2 s1 = *(const float2*)&ps[j][1][a2];
  float2 s2 = *(const float2*)&ps[j][2][a2];
  float2 s3 = *(const float2*)&ps[j][3][a2];
  float2 s4 = *(const float2*)&ps[j][4][a2];
  float2 s5 = *(const float2*)&ps[j][5][a2];
  float2 s6 = *(const float2*)&ps[j][6][a2];
  float2 s7 = *(const float2*)&ps[j][7][a2];
  float2 bz = *(const float2*)(bias + a2);
  float2 ev;
  ev.x = __builtin_amdgcn_exp2f(
      ((((s0.x + s1.x) + (s2.x + s3.x)) + ((s4.x + s5.x) + (s6.x + s7.x))) + bz.x) * TWO_LOG2E);
  ev.y = __builtin_amdgcn_exp2f(
      ((((s0.y + s1.y) + (s2.y + s3.y)) + ((s4.y + s5.y) + (s6.y + s7.y))) + bz.y) * TWO_LOG2E);

  if (isQ) {
    *(float2*)(Eq + (size_t)(r0 + j) * A + a2) = ev;   // coalesced per row
  } else {
    es[a2 + 0][j] = ev.x;
    es[a2 + 1][j] = ev.y;
    __syncthreads();
    int b  = r0 >> 10;          // TV == 1024
    int v0 = r0 & (TV - 1);
    for (int i = tid; i < A * 8; i += 512) {
      int aa = i >> 3, jj = i & 7;
      EkT[((size_t)b * A + aa) * TV + v0 + jj] = es[aa][jj];
    }
  }
}

// ---------------------------------------------------------------------------
// Scores + softmax.  ROUND-14: FOUR q rows per block, 1024 threads (16 waves),
// 256 blocks -> 1 block/CU, 16 waves/CU (50% occ).  Each thread owns ONE v.
// Per-thread lane work identical to the 2-row version (4 score-contribs per
// a-row), but each block's full 512KB EkT[b] read now serves 4 rows instead
// of 2 -> per-XCD L2 traffic halves (32MB -> 16MB).
// XCD map: xcd = blk&7 -> b = xcd&3 (ties batch to XCD's L2);
//          quad = (xcd>>2)*32 + (blk>>3)  in 0..63;  r0 = b*TQ + quad*4.
//   score[v] = sumV - 2 * sum_a v_a / (Eq[a]*EkT[a,v] + 1)
// ---------------------------------------------------------------------------
__global__ __launch_bounds__(1024, 4) void score_softmax_kernel(
    const float* __restrict__ Eq, const float* __restrict__ EkT,
    const float* __restrict__ attn_v, const int* __restrict__ mask,
    float* __restrict__ attn) {
  __shared__ float red[4][16];
  __shared__ float bc[8];

  int tid = threadIdx.x;
  int v0  = tid;                       // one v per thread, wave-contiguous
  int xcd = blockIdx.x & 7;
  int b   = xcd & 3;
  int quad = (xcd >> 2) * 32 + (blockIdx.x >> 3);   // 0..63
  int r0  = b * TQ + quad * 4;

  const float* eq0 = Eq + (size_t)(r0 + 0) * A;
  const float* eq1 = Eq + (size_t)(r0 + 1) * A;
  const float* eq2 = Eq + (size_t)(r0 + 2) * A;
  const float* eq3 = Eq + (size_t)(r0 + 3) * A;

  float sumV = 0.f;
#pragma unroll 16
  for (int i = 0; i < A; ++i) sumV += attn_v[i];

  const float* ekb = EkT + (size_t)b * A * TV + v0;
  float t[4] = {0.f, 0.f, 0.f, 0.f};

  float c[4], n[4];
#pragma unroll
  for (int aa = 0; aa < 4; ++aa) c[aa] = ekb[(size_t)aa * TV];

  for (int i = 0; i < A; i += 4) {
    if (i < A - 4) {
#pragma unroll
      for (int aa = 0; aa < 4; ++aa) n[aa] = ekb[(size_t)(i + 4 + aa) * TV];
    }
#pragma unroll
    for (int aa = 0; aa < 4; ++aa) {
      float av = attn_v[i + aa];                       // s_load (uniform)
      float q0v = eq0[i + aa], q1v = eq1[i + aa];      // s_load (uniform)
      float q2v = eq2[i + aa], q3v = eq3[i + aa];
      t[0] = fmaf(av, __builtin_amdgcn_rcpf(fmaf(c[aa], q0v, 1.f)), t[0]);
      t[1] = fmaf(av, __builtin_amdgcn_rcpf(fmaf(c[aa], q1v, 1.f)), t[1]);
      t[2] = fmaf(av, __builtin_amdgcn_rcpf(fmaf(c[aa], q2v, 1.f)), t[2]);
      t[3] = fmaf(av, __builtin_amdgcn_rcpf(fmaf(c[aa], q3v, 1.f)), t[3]);
    }
#pragma unroll
    for (int aa = 0; aa < 4; ++aa) c[aa] = n[aa];
  }

  int mk = mask[b * TV + v0];
  float mkv = (1.f - (float)mk) * NEG_BIG_F;
  float s[4];
#pragma unroll
  for (int r = 0; r < 4; ++r) s[r] = sumV - 2.f * t[r] + mkv;

  // ---- block max per row ----
  float m[4];
#pragma unroll
  for (int r = 0; r < 4; ++r) m[r] = s[r];
  for (int off = 32; off > 0; off >>= 1) {
#pragma unroll
    for (int r = 0; r < 4; ++r) m[r] = fmaxf(m[r], __shfl_down(m[r], off, 64));
  }
  int w = tid >> 6;              // wave 0..15
  if ((tid & 63) == 0) {
#pragma unroll
    for (int r = 0; r < 4; ++r) red[r][w] = m[r];
  }
  __syncthreads();
  if (tid < 4) {
    float a = red[tid][0];
#pragma unroll
    for (int i = 1; i < 16; ++i) a = fmaxf(a, red[tid][i]);
    bc[tid] = a;
  }
  __syncthreads();
  float M0 = bc[0], M1 = bc[1], M2 = bc[2], M3 = bc[3];

  // ---- exp + block sum per row ----
  float e[4];
  e[0] = __builtin_amdgcn_exp2f((s[0] - M0) * LOG2E);
  e[1] = __builtin_amdgcn_exp2f((s[1] - M1) * LOG2E);
  e[2] = __builtin_amdgcn_exp2f((s[2] - M2) * LOG2E);
  e[3] = __builtin_amdgcn_exp2f((s[3] - M3) * LOG2E);
  float l[4];
#pragma unroll
  for (int r = 0; r < 4; ++r) l[r] = e[r];
  for (int off = 32; off > 0; off >>= 1) {
#pragma unroll
    for (int r = 0; r < 4; ++r) l[r] += __shfl_down(l[r], off, 64);
  }
  __syncthreads();   // protect red[] before rewrite
  if ((tid & 63) == 0) {
#pragma unroll
    for (int r = 0; r < 4; ++r) red[r][w] = l[r];
  }
  __syncthreads();
  if (tid < 4) {
    float a = 0.f;
#pragma unroll
    for (int i = 0; i < 16; ++i) a += red[tid][i];
    bc[4 + tid] = a;
  }
  __syncthreads();
  float i0 = 1.f / bc[4], i1 = 1.f / bc[5], i2 = 1.f / bc[6], i3 = 1.f / bc[7];

  attn[(size_t)(r0 + 0) * TV + v0] = e[0] * i0;
  attn[(size_t)(r0 + 1) * TV + v0] = e[1] * i1;
  attn[(size_t)(r0 + 2) * TV + v0] = e[2] * i2;
  attn[(size_t)(r0 + 3) * TV + v0] = e[3] * i3;
}

// ---------------------------------------------------------------------------
// out[b,q,:] = sum_v attn[b,q,v] * inputs[b,v,:]   -- NO ATOMICS.
// ROUND-14: attn LDS staging REMOVED (Common-mistake #7: staging L2-resident
// data is pure overhead). attn is read directly from L2 with the same
// half-wave-broadcast addresses, prefetched one v-step ahead alongside X.
// Saves ~2048 ds_read_b128/CU + 2 barriers; LDS now only 32KB partials.
// Same XCD-swizzled map: g=blk&15 -> b=g&3, dt=g>>2; qt=blk>>4.
// 512 blocks x 512 thr -> 16 waves/CU.
// ---------------------------------------------------------------------------
__global__ __launch_bounds__(512, 4) void pv_kernel(
    const float* __restrict__ attn, const float* __restrict__ X,
    float* __restrict__ out) {
  __shared__ float lds[8 * 1024];    // 32 KB: 8 wave-partial tiles
  int gsl = blockIdx.x & 15;         // (b, dt) slice group
  int b   = gsl & 3;
  int dt  = gsl >> 2;                // 0..3, d-slice of 128
  int qt  = blockIdx.x >> 4;         // 0..31
  int q0  = b * TQ + qt * 8;         // global row (b*TQ + q)
  int tid  = threadIdx.x;
  int w    = tid >> 6;               // wave 0..7 -> v range [w*128, w*128+128)
  int lane = tid & 63;
  int col  = lane & 31;              // float4 d-column
  int qh   = lane >> 5;              // 0..1 -> q rows qh*4 .. qh*4+3
  int d0 = dt * 128 + col * 4;

  float4 acc[4];
#pragma unroll
  for (int j = 0; j < 4; ++j) acc[j] = make_float4(0.f, 0.f, 0.f, 0.f);

  int vbase = w * 128;
  const float* Xb = X + ((size_t)b * TV + vbase) * D + d0;
  const float* arow = attn + (size_t)(q0 + qh * 4) * TV + vbase;  // 4 rows

  float4 xc0 = *(const float4*)(Xb + (size_t)0 * D);
  float4 xc1 = *(const float4*)(Xb + (size_t)1 * D);
  float4 xc2 = *(const float4*)(Xb + (size_t)2 * D);
  float4 xc3 = *(const float4*)(Xb + (size_t)3 * D);
  float4 ac[4], an[4];
#pragma unroll
  for (int j = 0; j < 4; ++j)
    ac[j] = *(const float4*)(arow + (size_t)j * TV);   // 2-addr bcast loads

  for (int vi = 0; vi < 128; vi += 4) {
    float4 xn0, xn1, xn2, xn3;
    if (vi < 124) {
      const float* Xn = Xb + (size_t)(vi + 4) * D;
      xn0 = *(const float4*)(Xn + (size_t)0 * D);
      xn1 = *(const float4*)(Xn + (size_t)1 * D);
      xn2 = *(const float4*)(Xn + (size_t)2 * D);
      xn3 = *(const float4*)(Xn + (size_t)3 * D);
#pragma unroll
      for (int j = 0; j < 4; ++j)
        an[j] = *(const float4*)(arow + (size_t)j * TV + vi + 4);
    }
#pragma unroll
    for (int j = 0; j < 4; ++j) {
      float4 av = ac[j];
      acc[j].x = fmaf(av.x, xc0.x, acc[j].x);
      acc[j].y = fmaf(av.x, xc0.y, acc[j].y);
      acc[j].z = fmaf(av.x, xc0.z, acc[j].z);
      acc[j].w = fmaf(av.x, xc0.w, acc[j].w);
      acc[j].x = fmaf(av.y, xc1.x, acc[j].x);
      acc[j].y = fmaf(av.y, xc1.y, acc[j].y);
      acc[j].z = fmaf(av.y, xc1.z, acc[j].z);
      acc[j].w = fmaf(av.y, xc1.w, acc[j].w);
      acc[j].x = fmaf(av.z, xc2.x, acc[j].x);
      acc[j].y = fmaf(av.z, xc2.y, acc[j].y);
      acc[j].z = fmaf(av.z, xc2.z, acc[j].z);
      acc[j].w = fmaf(av.z, xc2.w, acc[j].w);
      acc[j].x = fmaf(av.w, xc3.x, acc[j].x);
      acc[j].y = fmaf(av.w, xc3.y, acc[j].y);
      acc[j].z = fmaf(av.w, xc3.z, acc[j].z);
      acc[j].w = fmaf(av.w, xc3.w, acc[j].w);
    }
    xc0 = xn0; xc1 = xn1; xc2 = xn2; xc3 = xn3;
#pragma unroll
    for (int j = 0; j < 4; ++j) ac[j] = an[j];
  }

  // write wave partials: lds[w][8 rows][32 float4 cols]
  {
    float4* pat = (float4*)lds + (size_t)w * 256;
#pragma unroll
    for (int j = 0; j < 4; ++j)
      pat[(qh * 4 + j) * 32 + col] = acc[j];
  }
  __syncthreads();

  // reduce 8 partials and store: 256 float4 outputs
  if (tid < 256) {
    int row = tid >> 5;            // 0..7
    int c   = tid & 31;            // 0..31
    const float4* p = (const float4*)lds + tid;  // == row*32 + c
    float4 r = p[0];
#pragma unroll
    for (int i = 1; i < 8; ++i) {
      float4 t = p[(size_t)i * 256];
      r.x += t.x; r.y += t.y; r.z += t.z; r.w += t.w;
    }
    *(float4*)(out + (size_t)(q0 + row) * D + dt * 128 + c * 4) = r;
  }
}

extern "C" void kernel_launch(void* const* d_in, const int* in_sizes, int n_in,
                              void* d_out, int out_size, void* d_ws, size_t ws_size,
                              hipStream_t stream) {
  const float* inputs  = (const float*)d_in[0];  // [B,TV,D]
  const float* context = (const float*)d_in[1];  // [B,TQ,D]
  const int*   mask    = (const int*)d_in[2];    // [B,TV]
  const float* Wk      = (const float*)d_in[3];  // [D,A]
  const float* bk      = (const float*)d_in[4];  // [A]
  const float* Wq      = (const float*)d_in[5];  // [D,A]
  const float* bq      = (const float*)d_in[6];  // [A]
  const float* attn_v  = (const float*)d_in[7];  // [A]
  float* out = (float*)d_out;                    // [B,TQ,D]

  // Workspace layout (fp32): Eq | EkT | attn  = 0.5MB + 2MB + 4MB
  float* Eq   = (float*)d_ws;             // [B*TQ, A]
  float* EkT  = Eq + B * TQ * A;          // [B, A, TV]  (transposed!)
  float* attn = EkT + (size_t)B * A * TV; // [B*TQ, TV]

  proj_exp_kernel<<<QBLK + KBLK, 512, 0, stream>>>(context, inputs, Wq, bq,
                                                   Wk, bk, Eq, EkT);
  score_softmax_kernel<<<B * TQ / 4, 1024, 0, stream>>>(Eq, EkT, attn_v, mask,
                                                        attn);
  pv_kernel<<<512, 512, 0, stream>>>(attn, inputs, out);
}

// Round 4
// 134.866 us; speedup vs baseline: 2.0343x; 1.0882x over previous
//
#include <hip/hip_runtime.h>
#include <math.h>

// Problem sizes (fixed by the reference)
#define B   4
#define TQ  256
#define TV  1024
#define D   512
#define A   128

#define LOG2E     1.4426950408889634f
#define TWO_LOG2E 2.8853900817779268f
#define NEG_BIG_F (-1e9f)

#define QBLK (B * TQ / 8)   // 128 q-projection blocks
#define KBLK (B * TV / 8)   // 512 k-projection blocks

// ---------------------------------------------------------------------------
// Fused projection + exp(2x) for BOTH q and k.  (proven, unchanged)
//   q path: Eq[r, a]     = exp(2*(ctx[r,:]@Wq[:,a] + bq[a]))   [row-major]
//   k path: EkT[b, a, v] = exp(2*(inp[r,:]@Wk[:,a] + bk[a]))   [TRANSPOSED]
// 512 threads (8 waves), d-split 8-way per wave (64 d each). All 64 lanes of
// a wave share X addresses -> s_load_dwordx4. Lane owns an a-pair x 8 rows.
// ---------------------------------------------------------------------------
__global__ __launch_bounds__(512, 4) void proj_exp_kernel(
    const float* __restrict__ ctx, const float* __restrict__ inp,
    const float* __restrict__ Wq, const float* __restrict__ bq,
    const float* __restrict__ Wk, const float* __restrict__ bk,
    float* __restrict__ Eq, float* __restrict__ EkT) {
  __shared__ float ps[8][8][A];     // 32 KB (row j, wave, a)
  __shared__ float es[A][9];        // 4.6 KB (transpose staging, +1 pad)

  bool isQ = blockIdx.x < QBLK;
  const float* X; const float* W; const float* bias; int r0;
  if (isQ) { X = ctx; W = Wq; bias = bq; r0 = blockIdx.x * 8; }
  else     { X = inp; W = Wk; bias = bk; r0 = (blockIdx.x - QBLK) * 8; }

  int tid = threadIdx.x;
  int ap = (tid & 63) * 2;      // a-pair base: 64 lanes cover a = 0..127
  int g  = tid >> 6;            // wave id 0..7  (wave-uniform)

  int dbase = __builtin_amdgcn_readfirstlane(g * 64);
  const float* Xr = X + (size_t)r0 * D + dbase;   // wave-uniform base
  const float* Wd = W + (size_t)dbase * A + ap;

  float2 acc[8];
#pragma unroll
  for (int j = 0; j < 8; ++j) acc[j] = make_float2(0.f, 0.f);

#pragma unroll 2
  for (int dd = 0; dd < 64; dd += 4) {
    float2 w0 = *(const float2*)(Wd + (size_t)(dd + 0) * A);
    float2 w1 = *(const float2*)(Wd + (size_t)(dd + 1) * A);
    float2 w2 = *(const float2*)(Wd + (size_t)(dd + 2) * A);
    float2 w3 = *(const float2*)(Wd + (size_t)(dd + 3) * A);
    float4 x[8];
#pragma unroll
    for (int j = 0; j < 8; ++j)
      x[j] = *(const float4*)(Xr + (size_t)j * D + dd);   // scalar s_load
#pragma unroll
    for (int j = 0; j < 8; ++j) {
      acc[j].x = fmaf(x[j].x, w0.x, acc[j].x);
      acc[j].y = fmaf(x[j].x, w0.y, acc[j].y);
      acc[j].x = fmaf(x[j].y, w1.x, acc[j].x);
      acc[j].y = fmaf(x[j].y, w1.y, acc[j].y);
      acc[j].x = fmaf(x[j].z, w2.x, acc[j].x);
      acc[j].y = fmaf(x[j].z, w2.y, acc[j].y);
      acc[j].x = fmaf(x[j].w, w3.x, acc[j].x);
      acc[j].y = fmaf(x[j].w, w3.y, acc[j].y);
    }
  }

#pragma unroll
  for (int j = 0; j < 8; ++j)
    *(float2*)&ps[j][g][ap] = acc[j];
  __syncthreads();

  // reduce 8 wave-partials: row j = tid>>6, a-pair per lane
  int j  = tid >> 6;            // 0..7
  int a2 = (tid & 63) * 2;
  float2 s0 = *(const float2*)&ps[j][0][a2];
  float2 s1 = *(const float2*)&ps[j][1][a2];
  float2 s2 = *(const float2*)&ps[j][2][a2];
  float2 s3 = *(const float2*)&ps[j][3][a2];
  float2 s4 = *(const float2*)&ps[j][4][a2];
  float2 s5 = *(const float2*)&ps[j][5][a2];
  float2 s6 = *(const float2*)&ps[j][6][a2];
  float2 s7 = *(const float2*)&ps[j][7][a2];
  float2 bz = *(const float2*)(bias + a2);
  float2 ev;
  ev.x = __builtin_amdgcn_exp2f(
      ((((s0.x + s1.x) + (s2.x + s3.x)) + ((s4.x + s5.x) + (s6.x + s7.x))) + bz.x) * TWO_LOG2E);
  ev.y = __builtin_amdgcn_exp2f(
      ((((s0.y + s1.y) + (s2.y + s3.y)) + ((s4.y + s5.y) + (s6.y + s7.y))) + bz.y) * TWO_LOG2E);

  if (isQ) {
    *(float2*)(Eq + (size_t)(r0 + j) * A + a2) = ev;   // coalesced per row
  } else {
    es[a2 + 0][j] = ev.x;
    es[a2 + 1][j] = ev.y;
    __syncthreads();
    int b  = r0 >> 10;          // TV == 1024
    int v0 = r0 & (TV - 1);
    for (int i = tid; i < A * 8; i += 512) {
      int aa = i >> 3, jj = i & 7;
      EkT[((size_t)b * A + aa) * TV + v0 + jj] = es[aa][jj];
    }
  }
}

// ---------------------------------------------------------------------------
// Scores + softmax.  ROUND-15: FOUR q rows per block but with the PROVEN
// round-0 structure: 512 threads (8 waves), float2 per thread, dist-1
// prefetch. 256 blocks (1 block/CU, 8 waves/CU). Each block's 512KB EkT[b]
// read now serves 4 rows -> per-XCD L2 traffic 32MB -> 16MB (halved).
// XCD map: xcd = blk&7 -> b = xcd&3;  quad = (xcd>>2)*32 + (blk>>3) in 0..63;
//          r0 = b*TQ + quad*4.
//   score[v] = sumV - 2 * sum_a v_a / (Eq[a]*EkT[a,v] + 1)
// ---------------------------------------------------------------------------
__global__ __launch_bounds__(512, 4) void score_softmax_kernel(
    const float* __restrict__ Eq, const float* __restrict__ EkT,
    const float* __restrict__ attn_v, const int* __restrict__ mask,
    float* __restrict__ attn) {
  __shared__ float red[4][8];
  __shared__ float bc[8];

  int tid = threadIdx.x;
  int v0  = (tid & 63) * 2 + (tid >> 6) * 128;  // wave-contiguous float2
  int xcd = blockIdx.x & 7;
  int b   = xcd & 3;
  int quad = (xcd >> 2) * 32 + (blockIdx.x >> 3);   // 0..63
  int r0  = b * TQ + quad * 4;

  const float* eq0 = Eq + (size_t)(r0 + 0) * A;
  const float* eq1 = Eq + (size_t)(r0 + 1) * A;
  const float* eq2 = Eq + (size_t)(r0 + 2) * A;
  const float* eq3 = Eq + (size_t)(r0 + 3) * A;

  float sumV = 0.f;
#pragma unroll 16
  for (int i = 0; i < A; ++i) sumV += attn_v[i];

  const float* ekb = EkT + (size_t)b * A * TV + v0;
  float2 t0 = make_float2(0.f, 0.f);
  float2 t1 = make_float2(0.f, 0.f);
  float2 t2 = make_float2(0.f, 0.f);
  float2 t3 = make_float2(0.f, 0.f);

  float2 c0 = *(const float2*)(ekb + (size_t)0 * TV);
  float2 c1 = *(const float2*)(ekb + (size_t)1 * TV);
  float2 c2 = *(const float2*)(ekb + (size_t)2 * TV);
  float2 c3 = *(const float2*)(ekb + (size_t)3 * TV);

  for (int i = 0; i < A; i += 4) {
    float2 n0, n1, n2, n3;
    if (i < A - 4) {
      n0 = *(const float2*)(ekb + (size_t)(i + 4) * TV);
      n1 = *(const float2*)(ekb + (size_t)(i + 5) * TV);
      n2 = *(const float2*)(ekb + (size_t)(i + 6) * TV);
      n3 = *(const float2*)(ekb + (size_t)(i + 7) * TV);
    }
#pragma unroll
    for (int aa = 0; aa < 4; ++aa) {
      float2 c = (aa == 0) ? c0 : (aa == 1) ? c1 : (aa == 2) ? c2 : c3;
      float av  = attn_v[i + aa];                 // uniform s_load
      float q0v = eq0[i + aa], q1v = eq1[i + aa]; // uniform s_load
      float q2v = eq2[i + aa], q3v = eq3[i + aa];
      t0.x = fmaf(av, __builtin_amdgcn_rcpf(fmaf(c.x, q0v, 1.f)), t0.x);
      t0.y = fmaf(av, __builtin_amdgcn_rcpf(fmaf(c.y, q0v, 1.f)), t0.y);
      t1.x = fmaf(av, __builtin_amdgcn_rcpf(fmaf(c.x, q1v, 1.f)), t1.x);
      t1.y = fmaf(av, __builtin_amdgcn_rcpf(fmaf(c.y, q1v, 1.f)), t1.y);
      t2.x = fmaf(av, __builtin_amdgcn_rcpf(fmaf(c.x, q2v, 1.f)), t2.x);
      t2.y = fmaf(av, __builtin_amdgcn_rcpf(fmaf(c.y, q2v, 1.f)), t2.y);
      t3.x = fmaf(av, __builtin_amdgcn_rcpf(fmaf(c.x, q3v, 1.f)), t3.x);
      t3.y = fmaf(av, __builtin_amdgcn_rcpf(fmaf(c.y, q3v, 1.f)), t3.y);
    }
    c0 = n0; c1 = n1; c2 = n2; c3 = n3;
  }

  int2 mk = *(const int2*)(mask + b * TV + v0);
  float mkx = (1.f - (float)mk.x) * NEG_BIG_F;
  float mky = (1.f - (float)mk.y) * NEG_BIG_F;
  float2 s[4];
  s[0].x = sumV - 2.f * t0.x + mkx;  s[0].y = sumV - 2.f * t0.y + mky;
  s[1].x = sumV - 2.f * t1.x + mkx;  s[1].y = sumV - 2.f * t1.y + mky;
  s[2].x = sumV - 2.f * t2.x + mkx;  s[2].y = sumV - 2.f * t2.y + mky;
  s[3].x = sumV - 2.f * t3.x + mkx;  s[3].y = sumV - 2.f * t3.y + mky;

  // ---- block max per row ----
  float m[4];
#pragma unroll
  for (int r = 0; r < 4; ++r) m[r] = fmaxf(s[r].x, s[r].y);
  for (int off = 32; off > 0; off >>= 1) {
#pragma unroll
    for (int r = 0; r < 4; ++r) m[r] = fmaxf(m[r], __shfl_down(m[r], off, 64));
  }
  int w = tid >> 6;              // wave 0..7
  if ((tid & 63) == 0) {
#pragma unroll
    for (int r = 0; r < 4; ++r) red[r][w] = m[r];
  }
  __syncthreads();
  if (tid < 4) {
    float a = red[tid][0];
#pragma unroll
    for (int i = 1; i < 8; ++i) a = fmaxf(a, red[tid][i]);
    bc[tid] = a;
  }
  __syncthreads();
  float M[4] = {bc[0], bc[1], bc[2], bc[3]};

  // ---- exp + block sum per row ----
  float2 e[4];
  float l[4];
#pragma unroll
  for (int r = 0; r < 4; ++r) {
    e[r].x = __builtin_amdgcn_exp2f((s[r].x - M[r]) * LOG2E);
    e[r].y = __builtin_amdgcn_exp2f((s[r].y - M[r]) * LOG2E);
    l[r] = e[r].x + e[r].y;
  }
  for (int off = 32; off > 0; off >>= 1) {
#pragma unroll
    for (int r = 0; r < 4; ++r) l[r] += __shfl_down(l[r], off, 64);
  }
  __syncthreads();   // protect red[] before rewrite
  if ((tid & 63) == 0) {
#pragma unroll
    for (int r = 0; r < 4; ++r) red[r][w] = l[r];
  }
  __syncthreads();
  if (tid < 4) {
    float a = 0.f;
#pragma unroll
    for (int i = 0; i < 8; ++i) a += red[tid][i];
    bc[4 + tid] = a;
  }
  __syncthreads();

#pragma unroll
  for (int r = 0; r < 4; ++r) {
    float inv = 1.f / bc[4 + r];
    *(float2*)(attn + (size_t)(r0 + r) * TV + v0) =
        make_float2(e[r].x * inv, e[r].y * inv);
  }
}

// ---------------------------------------------------------------------------
// out[b,q,:] = sum_v attn[b,q,v] * inputs[b,v,:]   -- NO ATOMICS.
// EXACT round-0 form (proven): attn tile staged in LDS (32x broadcast reuse
// justifies staging); XCD-swizzled 1-D block map: g=blk&15 -> b=g&3, dt=g>>2;
// qt=blk>>4. 512 blocks x 512 thr -> 16 waves/CU. 8 waves own disjoint 128-v
// chunks; partials reduced through 32 KB LDS.
// ---------------------------------------------------------------------------
__global__ __launch_bounds__(512, 4) void pv_kernel(
    const float* __restrict__ attn, const float* __restrict__ X,
    float* __restrict__ out) {
  __shared__ float lds[8 * 1024];    // 32 KB: attn tile, then 8 partial tiles
  int gsl = blockIdx.x & 15;         // (b, dt) slice group
  int b   = gsl & 3;
  int dt  = gsl >> 2;                // 0..3, d-slice of 128
  int qt  = blockIdx.x >> 4;         // 0..31
  int q0  = b * TQ + qt * 8;         // global row (b*TQ + q)
  int tid  = threadIdx.x;
  int w    = tid >> 6;               // wave 0..7 -> v range [w*128, w*128+128)
  int lane = tid & 63;
  int col  = lane & 31;              // float4 d-column
  int qh   = lane >> 5;              // 0..1 -> q rows qh*4 .. qh*4+3
  int d0 = dt * 128 + col * 4;

  // stage attn tile: 8 rows x 1024 v (float4, coalesced)
  {
    const float4* src = (const float4*)(attn + (size_t)q0 * TV);
    float4* dst = (float4*)lds;
    for (int i = tid; i < 8 * 256; i += 512) dst[i] = src[i];
  }
  __syncthreads();

  float4 acc[4];
#pragma unroll
  for (int j = 0; j < 4; ++j) acc[j] = make_float4(0.f, 0.f, 0.f, 0.f);

  int vbase = w * 128;
  const float* Xb = X + ((size_t)b * TV + vbase) * D + d0;
  const float* arow = &lds[(qh * 4) * 1024 + vbase];  // 4 rows, stride 1024

  float4 xc0 = *(const float4*)(Xb + (size_t)0 * D);
  float4 xc1 = *(const float4*)(Xb + (size_t)1 * D);
  float4 xc2 = *(const float4*)(Xb + (size_t)2 * D);
  float4 xc3 = *(const float4*)(Xb + (size_t)3 * D);

  for (int vi = 0; vi < 128; vi += 4) {
    float4 xn0, xn1, xn2, xn3;
    if (vi < 124) {
      const float* Xn = Xb + (size_t)(vi + 4) * D;
      xn0 = *(const float4*)(Xn + (size_t)0 * D);
      xn1 = *(const float4*)(Xn + (size_t)1 * D);
      xn2 = *(const float4*)(Xn + (size_t)2 * D);
      xn3 = *(const float4*)(Xn + (size_t)3 * D);
    }
#pragma unroll
    for (int j = 0; j < 4; ++j) {
      float4 av = *(const float4*)(arow + j * 1024 + vi);  // 2-addr bcast
      acc[j].x = fmaf(av.x, xc0.x, acc[j].x);
      acc[j].y = fmaf(av.x, xc0.y, acc[j].y);
      acc[j].z = fmaf(av.x, xc0.z, acc[j].z);
      acc[j].w = fmaf(av.x, xc0.w, acc[j].w);
      acc[j].x = fmaf(av.y, xc1.x, acc[j].x);
      acc[j].y = fmaf(av.y, xc1.y, acc[j].y);
      acc[j].z = fmaf(av.y, xc1.z, acc[j].z);
      acc[j].w = fmaf(av.y, xc1.w, acc[j].w);
      acc[j].x = fmaf(av.z, xc2.x, acc[j].x);
      acc[j].y = fmaf(av.z, xc2.y, acc[j].y);
      acc[j].z = fmaf(av.z, xc2.z, acc[j].z);
      acc[j].w = fmaf(av.z, xc2.w, acc[j].w);
      acc[j].x = fmaf(av.w, xc3.x, acc[j].x);
      acc[j].y = fmaf(av.w, xc3.y, acc[j].y);
      acc[j].z = fmaf(av.w, xc3.z, acc[j].z);
      acc[j].w = fmaf(av.w, xc3.w, acc[j].w);
    }
    xc0 = xn0; xc1 = xn1; xc2 = xn2; xc3 = xn3;
  }

  __syncthreads();   // everyone done READING the attn tile

  // write wave partials: lds[w][8 rows][32 float4 cols]
  {
    float4* pat = (float4*)lds + (size_t)w * 256;
#pragma unroll
    for (int j = 0; j < 4; ++j)
      pat[(qh * 4 + j) * 32 + col] = acc[j];
  }
  __syncthreads();

  // reduce 8 partials and store: 256 float4 outputs
  if (tid < 256) {
    int row = tid >> 5;            // 0..7
    int c   = tid & 31;            // 0..31
    const float4* p = (const float4*)lds + tid;  // == row*32 + c
    float4 r = p[0];
#pragma unroll
    for (int i = 1; i < 8; ++i) {
      float4 t = p[(size_t)i * 256];
      r.x += t.x; r.y += t.y; r.z += t.z; r.w += t.w;
    }
    *(float4*)(out + (size_t)(q0 + row) * D + dt * 128 + c * 4) = r;
  }
}

extern "C" void kernel_launch(void* const* d_in, const int* in_sizes, int n_in,
                              void* d_out, int out_size, void* d_ws, size_t ws_size,
                              hipStream_t stream) {
  const float* inputs  = (const float*)d_in[0];  // [B,TV,D]
  const float* context = (const float*)d_in[1];  // [B,TQ,D]
  const int*   mask    = (const int*)d_in[2];    // [B,TV]
  const float* Wk      = (const float*)d_in[3];  // [D,A]
  const float* bk      = (const float*)d_in[4];  // [A]
  const float* Wq      = (const float*)d_in[5];  // [D,A]
  const float* bq      = (const float*)d_in[6];  // [A]
  const float* attn_v  = (const float*)d_in[7];  // [A]
  float* out = (float*)d_out;                    // [B,TQ,D]

  // Workspace layout (fp32): Eq | EkT | attn  = 0.5MB + 2MB + 4MB
  float* Eq   = (float*)d_ws;             // [B*TQ, A]
  float* EkT  = Eq + B * TQ * A;          // [B, A, TV]  (transposed!)
  float* attn = EkT + (size_t)B * A * TV; // [B*TQ, TV]

  proj_exp_kernel<<<QBLK + KBLK, 512, 0, stream>>>(context, inputs, Wq, bq,
                                                   Wk, bk, Eq, EkT);
  score_softmax_kernel<<<B * TQ / 4, 512, 0, stream>>>(Eq, EkT, attn_v, mask,
                                                       attn);
  pv_kernel<<<512, 512, 0, stream>>>(attn, inputs, out);
}